// Round 5
// baseline (136.582 us; speedup 1.0000x reference)
//
#include <hip/hip_runtime.h>
#include <math.h>

#define NB 32    // batch
#define NS 128   // steps
#define NI 256   // in_dim
#define NC 128   // num capsules
#define ND 64    // dim capsule

#define L4 9.210340371976184f  // ln(10000)

// ---------------------------------------------------------------------------
// k_prep:
//   blocks [0,1024):      M[b,s,d] = sum_i u*W ; U[b,s] = sum_i u
//   blocks [1024,5120):   pe2n[n][s][d]  (n-major trig table)
//   blocks [5120,5152):   PE1[n][d]
// ---------------------------------------------------------------------------
__global__ __launch_bounds__(256) void k_prep(const float* __restrict__ u,
                                              const float* __restrict__ W,
                                              float* __restrict__ M,
                                              float* __restrict__ U,
                                              float* __restrict__ PE1,
                                              float* __restrict__ pe2n) {
    int blk = blockIdx.x;
    int t = threadIdx.x;
    if (blk < 1024) {
        int row = blk * 4 + (t >> 6);   // b*NS + s
        int d = t & 63;
        const float* ur = u + row * NI;
        float acc = 0.f, rs = 0.f;
#pragma unroll 4
        for (int i = 0; i < NI; ++i) {
            float v = ur[i];
            acc = fmaf(v, W[i * ND + d], acc);
            rs += v;
        }
        M[row * ND + d] = acc;
        if (d == 0) U[row] = rs;
    } else if (blk < 1024 + 4096) {
        int idx = (blk - 1024) * 256 + t;          // 1M elems, [n][s][d]
        int n = idx >> 13, s = (idx >> 6) & 127, d = idx & 63;
        int k2 = (n << 5) + (d >> 1);
        float g = __expf(-L4 * (float)k2 * (1.f / 4096.f));
        float sv, cv;
        __sincosf((float)s * g, &sv, &cv);
        pe2n[idx] = (d & 1) ? cv : sv;
    } else {
        int idx = (blk - 1024 - 4096) * 256 + t;   // 8192 elems, [n][d]
        int n = idx >> 6, d = idx & 63;
        float ang = (float)n * __expf(-L4 * (float)(d >> 1) * (1.f / 32.f));
        float sv, cv;
        __sincosf(ang, &sv, &cv);
        PE1[idx] = (d & 1) ? cv : sv;
    }
}

// ---------------------------------------------------------------------------
// kR v2: one routing iteration, one block per (b,n). 512 threads, ~9.5 KB LDS.
// Thread (sq=t>>4 in [0,32), dq=t&15) owns s = k*32+sq (k<4) of d-quad dq.
//   pass 1: u4[k] = M4 + PE1*U + pe2n4 kept in REGISTERS; acc += c[s]*u4[k].
//           Reduce acc over sq via LDS tree; squash scale computed once.
//   pass 2: p = dot(u4[k], outs4[dq]) per owned s; scalar LDS write
//           red[s][dq] (2-way banks, free); 128 threads sum 16 via b128 reads.
// No u-hat LDS tile at all: LDS traffic ~20x lower than v1, occupancy
// 4 blocks x 8 waves = 32 waves/CU (max). grid = 4096.
// ---------------------------------------------------------------------------
__global__ __launch_bounds__(512) void kR(const float* __restrict__ M,
                                          const float* __restrict__ U,
                                          const float* __restrict__ PE1,
                                          const float* __restrict__ pe2n,
                                          const float* __restrict__ cg,
                                          const float* __restrict__ mask,
                                          float* __restrict__ og,
                                          float* __restrict__ bl,
                                          int first, int last) {
    int bn = blockIdx.x;
    int b = bn >> 7, n = bn & 127;
    int t = threadIdx.x;

    __shared__ float4 red4[32][16];     // pass-1 partials; aliased by red2 in pass 2
    __shared__ float4 outs4[16];        // unscaled out_pre, d-quads
    __shared__ float cs_[NS], Us_[NS], ssp[16], scal[1];

    if (t < NS) {
        Us_[t] = U[b * NS + t];
        cs_[t] = first ? mask[b * NS + t] * (1.f / 128.f) : cg[bn * NS + t];
    }
    int dq = t & 15, sq = t >> 4;
    float4 p14 = ((const float4*)PE1)[n * 16 + dq];
    __syncthreads();

    const float4* M4 = (const float4*)M + (b * NS) * 16;
    const float4* P4 = (const float4*)pe2n + (n * NS) * 16;

    float4 u4[4];
    float4 acc = make_float4(0.f, 0.f, 0.f, 0.f);
#pragma unroll
    for (int k = 0; k < 4; ++k) {
        int s = k * 32 + sq;
        float4 m4 = M4[s * 16 + dq];
        float4 p4 = P4[s * 16 + dq];
        float uu = Us_[s], cc = cs_[s];
        float4 v;
        v.x = fmaf(p14.x, uu, m4.x) + p4.x;
        v.y = fmaf(p14.y, uu, m4.y) + p4.y;
        v.z = fmaf(p14.z, uu, m4.z) + p4.z;
        v.w = fmaf(p14.w, uu, m4.w) + p4.w;
        u4[k] = v;
        acc.x = fmaf(cc, v.x, acc.x);
        acc.y = fmaf(cc, v.y, acc.y);
        acc.z = fmaf(cc, v.z, acc.z);
        acc.w = fmaf(cc, v.w, acc.w);
    }
    red4[sq][dq] = acc;
    __syncthreads();

    // tree-reduce 32 sq partials -> 16
    if (t < 256) {
        int h = t >> 4;
        float4 a = red4[h][dq], c2 = red4[h + 16][dq];
        a.x += c2.x; a.y += c2.y; a.z += c2.z; a.w += c2.w;
        red4[h][dq] = a;
    }
    __syncthreads();
    if (t < 16) {
        float4 o = make_float4(0.f, 0.f, 0.f, 0.f);
#pragma unroll
        for (int q = 0; q < 16; ++q) {
            float4 r = red4[q][t];
            o.x += r.x; o.y += r.y; o.z += r.z; o.w += r.w;
        }
        outs4[t] = o;
        ssp[t] = o.x * o.x + o.y * o.y + o.z * o.z + o.w * o.w;
    }
    __syncthreads();
    if (t == 0) {
        float ss = 0.f;
#pragma unroll
        for (int j = 0; j < 16; ++j) ss += ssp[j];
        scal[0] = ss / (1.f + ss) * rsqrtf(ss + 1e-7f);
    }
    __syncthreads();
    float scale = scal[0];

    if (last) {
        if (t < 16) {
            float4 o = outs4[t];
            o.x *= scale; o.y *= scale; o.z *= scale; o.w *= scale;
            ((float4*)og)[bn * 16 + t] = o;
        }
        return;
    }

    // pass 2: bl[s] = scale * sum_d out_u[d] * uh[s][d]  (u-hat from registers)
    float4 o4 = outs4[dq];              // same-addr broadcast within bank group
    float* red2 = (float*)red4;         // reuse as [128][16]
#pragma unroll
    for (int k = 0; k < 4; ++k) {
        int s = k * 32 + sq;
        float4 v = u4[k];
        red2[s * 16 + dq] = v.x * o4.x + v.y * o4.y + v.z * o4.z + v.w * o4.w;
    }
    __syncthreads();
    if (t < NS) {
        const float4* r4 = (const float4*)(red2 + t * 16);
        float4 a = r4[0], b2 = r4[1], c2 = r4[2], d2 = r4[3];
        float a2 = a.x + a.y + a.z + a.w + b2.x + b2.y + b2.z + b2.w
                 + c2.x + c2.y + c2.z + c2.w + d2.x + d2.y + d2.z + d2.w;
        bl[bn * NS + t] = scale * a2;
    }
}

// ---------------------------------------------------------------------------
// kS: softmax over n for each (b,s); c[b,n,s] = softmax_n(bl[b,n,s])*mask.
// bl/c layout [b][n][s]. Block = (b, 16-s tile), 256 thr. grid = 256.
// ---------------------------------------------------------------------------
__global__ __launch_bounds__(256) void kS(const float* __restrict__ bl,
                                          const float* __restrict__ mask,
                                          float* __restrict__ c) {
    int blk = blockIdx.x;
    int b = blk >> 3, s0 = (blk & 7) * 16;
    int t = threadIdx.x;

    __shared__ float tl[NC][17];
    __shared__ float pr[16][17];
    __shared__ float ps[16][17];
    __shared__ float itot[16], msk[16];

    if (t < 16) msk[t] = mask[b * NS + s0 + t];
#pragma unroll
    for (int i = 0; i < 8; ++i) {
        int idx = i * 256 + t;
        int n = idx >> 4, si = idx & 15;
        tl[n][si] = bl[(b * NC + n) * NS + s0 + si];
    }
    __syncthreads();

    int si = t & 15, ch = t >> 4;      // 16 chunks x 8 n each
    float mx = -1e30f;
#pragma unroll
    for (int j = 0; j < 8; ++j) mx = fmaxf(mx, tl[ch * 8 + j][si]);
    pr[ch][si] = mx;
    __syncthreads();

    mx = pr[0][si];
#pragma unroll
    for (int jc = 1; jc < 16; ++jc) mx = fmaxf(mx, pr[jc][si]);
    float sm = 0.f;
#pragma unroll
    for (int j = 0; j < 8; ++j) {
        float e = __expf(tl[ch * 8 + j][si] - mx);
        tl[ch * 8 + j][si] = e;       // owner-exclusive rows: no race
        sm += e;
    }
    ps[ch][si] = sm;
    __syncthreads();

    if (t < 16) {
        float tot = 0.f;
#pragma unroll
        for (int jc = 0; jc < 16; ++jc) tot += ps[jc][t];
        itot[t] = msk[t] / tot;
    }
    __syncthreads();

#pragma unroll
    for (int i = 0; i < 8; ++i) {
        int idx = i * 256 + t;
        int n = idx >> 4, sj = idx & 15;
        c[(b * NC + n) * NS + s0 + sj] = tl[n][sj] * itot[sj];
    }
}

// ---------------------------------------------------------------------------
extern "C" void kernel_launch(void* const* d_in, const int* in_sizes, int n_in,
                              void* d_out, int out_size, void* d_ws, size_t ws_size,
                              hipStream_t stream) {
    const float* u    = (const float*)d_in[0];  // (32,128,256)
    const float* mask = (const float*)d_in[1];  // (32,128)
    const float* W    = (const float*)d_in[2];  // (1,256,64)
    float* out = (float*)d_out;                 // (32,128,64) = [b][n][d]

    float* ws   = (float*)d_ws;
    float* M    = ws;                           // 262144
    float* U    = M + NB * NS * ND;             // 4096
    float* PE1  = U + NB * NS;                  // 8192
    float* pe2n = PE1 + NC * ND;                // 1048576
    float* c    = pe2n + NC * NS * ND;          // 524288  [b][n][s]
    float* bl   = c + NB * NC * NS;             // 524288  [b][n][s]

    k_prep<<<5152, 256, 0, stream>>>(u, W, M, U, PE1, pe2n);

    // iter 0 (uniform c = mask/128) -> logits bl
    kR<<<NB * NC, 512, 0, stream>>>(M, U, PE1, pe2n, c, mask, out, bl, 1, 0);
    kS<<<NB * 8, 256, 0, stream>>>(bl, mask, c);
    // iter 1 -> logits bl
    kR<<<NB * NC, 512, 0, stream>>>(M, U, PE1, pe2n, c, mask, out, bl, 0, 0);
    kS<<<NB * 8, 256, 0, stream>>>(bl, mask, c);
    // iter 2 (final) -> d_out
    kR<<<NB * NC, 512, 0, stream>>>(M, U, PE1, pe2n, c, mask, out, bl, 0, 1);
}

// Round 6
// 126.427 us; speedup vs baseline: 1.0803x; 1.0803x over previous
//
#include <hip/hip_runtime.h>
#include <math.h>

#define NB 32    // batch
#define NS 128   // steps
#define NI 256   // in_dim
#define NC 128   // num capsules
#define ND 64    // dim capsule

#define L4 9.210340371976184f  // ln(10000)

// ---------------------------------------------------------------------------
// k_prep:
//   blocks [0,1024):      M[b,s,d] = sum_i u*W ; U[b,s] = sum_i u
//   blocks [1024,1056):   PE1[n][d]
// (pe2 is computed on the fly in kR now — no 4 MB table, no L2 thrash)
// ---------------------------------------------------------------------------
__global__ __launch_bounds__(256) void k_prep(const float* __restrict__ u,
                                              const float* __restrict__ W,
                                              float* __restrict__ M,
                                              float* __restrict__ U,
                                              float* __restrict__ PE1) {
    int blk = blockIdx.x;
    int t = threadIdx.x;
    if (blk < 1024) {
        int row = blk * 4 + (t >> 6);   // b*NS + s
        int d = t & 63;
        const float* ur = u + row * NI;
        float acc = 0.f, rs = 0.f;
#pragma unroll 4
        for (int i = 0; i < NI; ++i) {
            float v = ur[i];
            acc = fmaf(v, W[i * ND + d], acc);
            rs += v;
        }
        M[row * ND + d] = acc;
        if (d == 0) U[row] = rs;
    } else {
        int idx = (blk - 1024) * 256 + t;   // 8192 elems, [n][d]
        int n = idx >> 6, d = idx & 63;
        float ang = (float)n * __expf(-L4 * (float)(d >> 1) * (1.f / 32.f));
        float sv, cv;
        __sincosf(ang, &sv, &cv);
        PE1[idx] = (d & 1) ? cv : sv;
    }
}

// ---------------------------------------------------------------------------
// kR v3: one routing iteration, one block per (b,n). 512 threads, ~9.5 KB LDS.
// Thread (sq=t>>4 in [0,32), dq=t&15) owns s = k*32+sq (k<4) of d-quad dq.
// pe2[s, n*64+d] computed in-register: g0,g1 = exp(-ln1e4*(n*32+2dq+{0,1})/4096)
// hoisted (per-thread constants); per s just 2 muls + 2 sincos.
//   pass 1: u4 = M4 + PE1*U + pe2 in REGISTERS; acc += c[s]*u4; LDS tree
//           reduce over sq; squash scale once.
//   pass 2: dot(u4, outs4[dq]) per owned s -> scalar LDS (2-way banks, free);
//           128 threads sum 16 partials via 4x b128 reads; store bl coalesced.
// Global traffic: M[b] only (32 KB/block, L2-resident ~1 MB/XCD working set).
// grid = 4096, 32 waves/CU resident.
// ---------------------------------------------------------------------------
__global__ __launch_bounds__(512) void kR(const float* __restrict__ M,
                                          const float* __restrict__ U,
                                          const float* __restrict__ PE1,
                                          const float* __restrict__ cg,
                                          const float* __restrict__ mask,
                                          float* __restrict__ og,
                                          float* __restrict__ bl,
                                          int first, int last) {
    int bn = blockIdx.x;
    int b = bn >> 7, n = bn & 127;
    int t = threadIdx.x;

    __shared__ float4 red4[32][16];     // pass-1 partials; aliased by red2 in pass 2
    __shared__ float4 outs4[16];        // unscaled out_pre, d-quads
    __shared__ float cs_[NS], Us_[NS], ssp[16], scal[1];

    if (t < NS) {
        Us_[t] = U[b * NS + t];
        cs_[t] = first ? mask[b * NS + t] * (1.f / 128.f) : cg[bn * NS + t];
    }
    int dq = t & 15, sq = t >> 4;
    float4 p14 = ((const float4*)PE1)[n * 16 + dq];

    // per-thread pe2 frequency factors (depend only on n, dq)
    int k2 = n * 32 + dq * 2;
    float g0 = __expf(-L4 * (float)k2 * (1.f / 4096.f));
    float g1 = __expf(-L4 * (float)(k2 + 1) * (1.f / 4096.f));
    __syncthreads();

    const float4* M4 = (const float4*)M + (b * NS) * 16;

    float4 u4[4];
    float4 acc = make_float4(0.f, 0.f, 0.f, 0.f);
#pragma unroll
    for (int k = 0; k < 4; ++k) {
        int s = k * 32 + sq;
        float4 m4 = M4[s * 16 + dq];
        float uu = Us_[s], cc = cs_[s];
        float sf = (float)s;
        float s0, c0, s1, c1;
        __sincosf(sf * g0, &s0, &c0);
        __sincosf(sf * g1, &s1, &c1);
        float4 v;
        v.x = fmaf(p14.x, uu, m4.x) + s0;
        v.y = fmaf(p14.y, uu, m4.y) + c0;
        v.z = fmaf(p14.z, uu, m4.z) + s1;
        v.w = fmaf(p14.w, uu, m4.w) + c1;
        u4[k] = v;
        acc.x = fmaf(cc, v.x, acc.x);
        acc.y = fmaf(cc, v.y, acc.y);
        acc.z = fmaf(cc, v.z, acc.z);
        acc.w = fmaf(cc, v.w, acc.w);
    }
    red4[sq][dq] = acc;
    __syncthreads();

    // tree-reduce 32 sq partials -> 16
    if (t < 256) {
        int h = t >> 4;
        float4 a = red4[h][dq], c2 = red4[h + 16][dq];
        a.x += c2.x; a.y += c2.y; a.z += c2.z; a.w += c2.w;
        red4[h][dq] = a;
    }
    __syncthreads();
    if (t < 16) {
        float4 o = make_float4(0.f, 0.f, 0.f, 0.f);
#pragma unroll
        for (int q = 0; q < 16; ++q) {
            float4 r = red4[q][t];
            o.x += r.x; o.y += r.y; o.z += r.z; o.w += r.w;
        }
        outs4[t] = o;
        ssp[t] = o.x * o.x + o.y * o.y + o.z * o.z + o.w * o.w;
    }
    __syncthreads();
    if (t == 0) {
        float ss = 0.f;
#pragma unroll
        for (int j = 0; j < 16; ++j) ss += ssp[j];
        scal[0] = ss / (1.f + ss) * rsqrtf(ss + 1e-7f);
    }
    __syncthreads();
    float scale = scal[0];

    if (last) {
        if (t < 16) {
            float4 o = outs4[t];
            o.x *= scale; o.y *= scale; o.z *= scale; o.w *= scale;
            ((float4*)og)[bn * 16 + t] = o;
        }
        return;
    }

    // pass 2: bl[s] = scale * sum_d out_u[d] * uh[s][d]  (u-hat from registers)
    float4 o4 = outs4[dq];              // same-addr broadcast
    float* red2 = (float*)red4;         // reuse as [128][16]
#pragma unroll
    for (int k = 0; k < 4; ++k) {
        int s = k * 32 + sq;
        float4 v = u4[k];
        red2[s * 16 + dq] = v.x * o4.x + v.y * o4.y + v.z * o4.z + v.w * o4.w;
    }
    __syncthreads();
    if (t < NS) {
        const float4* r4 = (const float4*)(red2 + t * 16);
        float4 a = r4[0], b2 = r4[1], c2 = r4[2], d2 = r4[3];
        float a2 = a.x + a.y + a.z + a.w + b2.x + b2.y + b2.z + b2.w
                 + c2.x + c2.y + c2.z + c2.w + d2.x + d2.y + d2.z + d2.w;
        bl[bn * NS + t] = scale * a2;
    }
}

// ---------------------------------------------------------------------------
// kS: softmax over n for each (b,s); c[b,n,s] = softmax_n(bl[b,n,s])*mask.
// bl/c layout [b][n][s]. Block = (b, 16-s tile), 256 thr. grid = 256.
// ---------------------------------------------------------------------------
__global__ __launch_bounds__(256) void kS(const float* __restrict__ bl,
                                          const float* __restrict__ mask,
                                          float* __restrict__ c) {
    int blk = blockIdx.x;
    int b = blk >> 3, s0 = (blk & 7) * 16;
    int t = threadIdx.x;

    __shared__ float tl[NC][17];
    __shared__ float pr[16][17];
    __shared__ float ps[16][17];
    __shared__ float itot[16], msk[16];

    if (t < 16) msk[t] = mask[b * NS + s0 + t];
#pragma unroll
    for (int i = 0; i < 8; ++i) {
        int idx = i * 256 + t;
        int n = idx >> 4, si = idx & 15;
        tl[n][si] = bl[(b * NC + n) * NS + s0 + si];
    }
    __syncthreads();

    int si = t & 15, ch = t >> 4;      // 16 chunks x 8 n each
    float mx = -1e30f;
#pragma unroll
    for (int j = 0; j < 8; ++j) mx = fmaxf(mx, tl[ch * 8 + j][si]);
    pr[ch][si] = mx;
    __syncthreads();

    mx = pr[0][si];
#pragma unroll
    for (int jc = 1; jc < 16; ++jc) mx = fmaxf(mx, pr[jc][si]);
    float sm = 0.f;
#pragma unroll
    for (int j = 0; j < 8; ++j) {
        float e = __expf(tl[ch * 8 + j][si] - mx);
        tl[ch * 8 + j][si] = e;       // owner-exclusive rows: no race
        sm += e;
    }
    ps[ch][si] = sm;
    __syncthreads();

    if (t < 16) {
        float tot = 0.f;
#pragma unroll
        for (int jc = 0; jc < 16; ++jc) tot += ps[jc][t];
        itot[t] = msk[t] / tot;
    }
    __syncthreads();

#pragma unroll
    for (int i = 0; i < 8; ++i) {
        int idx = i * 256 + t;
        int n = idx >> 4, sj = idx & 15;
        c[(b * NC + n) * NS + s0 + sj] = tl[n][sj] * itot[sj];
    }
}

// ---------------------------------------------------------------------------
extern "C" void kernel_launch(void* const* d_in, const int* in_sizes, int n_in,
                              void* d_out, int out_size, void* d_ws, size_t ws_size,
                              hipStream_t stream) {
    const float* u    = (const float*)d_in[0];  // (32,128,256)
    const float* mask = (const float*)d_in[1];  // (32,128)
    const float* W    = (const float*)d_in[2];  // (1,256,64)
    float* out = (float*)d_out;                 // (32,128,64) = [b][n][d]

    float* ws  = (float*)d_ws;
    float* M   = ws;                            // 262144
    float* U   = M + NB * NS * ND;              // 4096
    float* PE1 = U + NB * NS;                   // 8192
    float* c   = PE1 + NC * ND;                 // 524288  [b][n][s]
    float* bl  = c + NB * NC * NS;              // 524288  [b][n][s]

    k_prep<<<1056, 256, 0, stream>>>(u, W, M, U, PE1);

    // iter 0 (uniform c = mask/128) -> logits bl
    kR<<<NB * NC, 512, 0, stream>>>(M, U, PE1, c, mask, out, bl, 1, 0);
    kS<<<NB * 8, 256, 0, stream>>>(bl, mask, c);
    // iter 1 -> logits bl
    kR<<<NB * NC, 512, 0, stream>>>(M, U, PE1, c, mask, out, bl, 0, 0);
    kS<<<NB * 8, 256, 0, stream>>>(bl, mask, c);
    // iter 2 (final) -> d_out
    kR<<<NB * NC, 512, 0, stream>>>(M, U, PE1, c, mask, out, bl, 0, 1);
}